// Round 4
// baseline (107.888 us; speedup 1.0000x reference)
//
#include <hip/hip_runtime.h>

#define Bdim 8
#define Mdim 64
#define Tdim 256
#define MTdim 320
#define Ddim 64
#define EPSF 1e-4f

__device__ __forceinline__ void load_lds16(const void* g, void* l) {
    __builtin_amdgcn_global_load_lds(
        (const __attribute__((address_space(1))) void*)g,
        (__attribute__((address_space(3))) void*)l, 16, 0, 0);
}

// ---------------------------------------------------------------------------
// Phase 1 v3: u[b,i,t,d] = sum_k W[i,t,d,k] * cat[b,t,k]
// One block (4 waves) per t-PAIR: double-buffered 2x16KB W tiles with
// counted-vmcnt pipeline (T3/T4-lite). LDS content XOR-swizzled:
// chunk k4 of row d at byte d*256 + ((k4 ^ (d&7))*16); source address
// pre-swizzled (linear LDS dest, rule #21). Wave w computes b=2w,2w+1.
// ---------------------------------------------------------------------------
__global__ __launch_bounds__(256) void u_kernel(
    const float* __restrict__ M_emb,
    const float* __restrict__ Ht,
    const float* __restrict__ W,
    float* __restrict__ u,
    int i0, int icap)
{
    const int tp  = blockIdx.x;                  // tile pair 0..159
    const int t0  = tp * 2, t1 = t0 + 1;
    const int ii  = blockIdx.y;
    const int i   = i0 + ii;
    const int tid = (int)threadIdx.x;
    const int l   = tid & 63;
    const int w   = __builtin_amdgcn_readfirstlane(tid >> 6);  // wave 0..3

    __shared__ __align__(16) float wtile[2 * 64 * 64];   // 32 KB
    char* ldsb = (char*)wtile;

    const char* wt0 = (const char*)(W + (((size_t)i * MTdim + t0) << 12));
    const char* wt1 = wt0 + 16384;

    // ---- stage both tiles: 8 x 1KB instructions per wave ----
#pragma unroll
    for (int s = 0; s < 4; ++s) {
        const int r   = w * 16 + s * 4 + (l >> 4);
        const int src = (r * 256 + ((l & 15) * 16)) ^ ((r & 7) * 16);
        load_lds16(wt0 + src, ldsb + (w * 4096 + s * 1024));
    }
#pragma unroll
    for (int s = 0; s < 4; ++s) {
        const int r   = w * 16 + s * 4 + (l >> 4);
        const int src = (r * 256 + ((l & 15) * 16)) ^ ((r & 7) * 16);
        load_lds16(wt1 + src, ldsb + 16384 + (w * 4096 + s * 1024));
    }

    // ---- wave-uniform cat row pointers for t0/t1, b = 2w,2w+1 ----
    const int b0 = 2 * w, b1 = 2 * w + 1;
    const float* c00;  const float* c01;   // batch b0, t0/t1
    const float* c10;  const float* c11;   // batch b1, t0/t1
    if (t0 < Mdim) {
        c00 = M_emb + (((size_t)b0 * Mdim + t0) << 6);
        c10 = M_emb + (((size_t)b1 * Mdim + t0) << 6);
    } else {
        c00 = Ht + (((size_t)b0 * Tdim + (t0 - Mdim)) << 6);
        c10 = Ht + (((size_t)b1 * Tdim + (t0 - Mdim)) << 6);
    }
    if (t1 < Mdim) {
        c01 = M_emb + (((size_t)b0 * Mdim + t1) << 6);
        c11 = M_emb + (((size_t)b1 * Mdim + t1) << 6);
    } else {
        c01 = Ht + (((size_t)b0 * Tdim + (t1 - Mdim)) << 6);
        c11 = Ht + (((size_t)b1 * Tdim + (t1 - Mdim)) << 6);
    }

    const int rbase = l * 256 + (l & 7) * 16;

    // ---- wait own tile-0 loads (4 newest = tile1 stay in flight) ----
    asm volatile("s_waitcnt vmcnt(4)" ::: "memory");
    __builtin_amdgcn_s_barrier();

    // ---- compute tile 0 ----
    {
        float a0 = 0.0f, a1 = 0.0f;
#pragma unroll
        for (int k4 = 0; k4 < 16; ++k4) {
            const float4 w4 = *reinterpret_cast<const float4*>(ldsb + (rbase ^ (k4 * 16)));
            const float4 p  = *reinterpret_cast<const float4*>(c00 + (k4 << 2));
            const float4 q  = *reinterpret_cast<const float4*>(c10 + (k4 << 2));
            a0 = fmaf(w4.x, p.x, a0); a0 = fmaf(w4.y, p.y, a0);
            a0 = fmaf(w4.z, p.z, a0); a0 = fmaf(w4.w, p.w, a0);
            a1 = fmaf(w4.x, q.x, a1); a1 = fmaf(w4.y, q.y, a1);
            a1 = fmaf(w4.z, q.z, a1); a1 = fmaf(w4.w, q.w, a1);
        }
        u[((((size_t)b0 * icap + ii) * MTdim + t0) << 6) + l] = a0;
        u[((((size_t)b1 * icap + ii) * MTdim + t0) << 6) + l] = a1;
    }

    // ---- own tile-1 loads done (4 oldest of 6: 2 stores may ride) ----
    asm volatile("s_waitcnt vmcnt(2)" ::: "memory");
    __builtin_amdgcn_s_barrier();

    // ---- compute tile 1 ----
    {
        float a0 = 0.0f, a1 = 0.0f;
#pragma unroll
        for (int k4 = 0; k4 < 16; ++k4) {
            const float4 w4 = *reinterpret_cast<const float4*>(ldsb + 16384 + (rbase ^ (k4 * 16)));
            const float4 p  = *reinterpret_cast<const float4*>(c01 + (k4 << 2));
            const float4 q  = *reinterpret_cast<const float4*>(c11 + (k4 << 2));
            a0 = fmaf(w4.x, p.x, a0); a0 = fmaf(w4.y, p.y, a0);
            a0 = fmaf(w4.z, p.z, a0); a0 = fmaf(w4.w, p.w, a0);
            a1 = fmaf(w4.x, q.x, a1); a1 = fmaf(w4.y, q.y, a1);
            a1 = fmaf(w4.z, q.z, a1); a1 = fmaf(w4.w, q.w, a1);
        }
        u[((((size_t)b0 * icap + ii) * MTdim + t1) << 6) + l] = a0;
        u[((((size_t)b1 * icap + ii) * MTdim + t1) << 6) + l] = a1;
    }
}

// ---------------------------------------------------------------------------
// Phase 2 (unchanged from R2): one block of 320 threads per (b,i);
// thread t holds u[t,0:63] in registers for all 3 iterations.
// ---------------------------------------------------------------------------
__device__ __forceinline__ float4 shfl_xor4(float4 v, int m) {
    float4 r;
    r.x = __shfl_xor(v.x, m, 64);
    r.y = __shfl_xor(v.y, m, 64);
    r.z = __shfl_xor(v.z, m, 64);
    r.w = __shfl_xor(v.w, m, 64);
    return r;
}
__device__ __forceinline__ float4 add4(float4 a, float4 b) {
    float4 r; r.x = a.x + b.x; r.y = a.y + b.y; r.z = a.z + b.z; r.w = a.w + b.w;
    return r;
}

__global__ __launch_bounds__(320) void iter_kernel(
    const float* __restrict__ u,
    const float* __restrict__ m_init,
    float* __restrict__ out,
    int i0, int icap)
{
    const int ii   = blockIdx.x;
    const int i    = i0 + ii;
    const int b    = blockIdx.y;
    const int tid  = (int)threadIdx.x;   // 0..319 == row t
    const int lane = tid & 63;
    const int w    = tid >> 6;           // 0..4

    const float* ub = u + ((((size_t)b * icap + ii) * MTdim) << 6);

    __shared__ __align__(16) float m_lds[Ddim];
    __shared__ float wmax[5], wsum[5];
    __shared__ float partial[5 * 64];

    float4 u4[16];
    {
        const float* row = ub + ((size_t)tid << 6);
#pragma unroll
        for (int k4 = 0; k4 < 16; ++k4)
            u4[k4] = *reinterpret_cast<const float4*>(row + (k4 << 2));
    }

    if (tid < Ddim)
        m_lds[tid] = m_init[(((size_t)b * Mdim + i) << 6) + tid];
    __syncthreads();

    for (int iter = 0; iter < 3; ++iter) {
        float bt = 0.0f;
#pragma unroll
        for (int k4 = 0; k4 < 16; ++k4) {
            float4 mv = *reinterpret_cast<const float4*>(&m_lds[k4 << 2]);
            bt = fmaf(u4[k4].x, mv.x, bt);
            bt = fmaf(u4[k4].y, mv.y, bt);
            bt = fmaf(u4[k4].z, mv.z, bt);
            bt = fmaf(u4[k4].w, mv.w, bt);
        }

        float mx = bt;
#pragma unroll
        for (int off = 1; off < 64; off <<= 1)
            mx = fmaxf(mx, __shfl_xor(mx, off, 64));
        if (lane == 0) wmax[w] = mx;
        __syncthreads();
        const float bmax = fmaxf(fmaxf(fmaxf(wmax[0], wmax[1]),
                                       fmaxf(wmax[2], wmax[3])), wmax[4]);

        const float e = expf(bt - bmax);

        float sm = e;
#pragma unroll
        for (int off = 1; off < 64; off <<= 1)
            sm += __shfl_xor(sm, off, 64);
        if (lane == 0) wsum[w] = sm;

        float4 c8[8];
#pragma unroll
        for (int jj = 0; jj < 8; ++jj) {
            const bool up = (lane & 32) != 0;
            float4 keep = up ? u4[jj + 8] : u4[jj];
            float4 give = up ? u4[jj] : u4[jj + 8];
            float4 g; g.x = give.x * e; g.y = give.y * e;
                      g.z = give.z * e; g.w = give.w * e;
            float4 r = shfl_xor4(g, 32);
            float4 o;
            o.x = fmaf(keep.x, e, r.x); o.y = fmaf(keep.y, e, r.y);
            o.z = fmaf(keep.z, e, r.z); o.w = fmaf(keep.w, e, r.w);
            c8[jj] = o;
        }
        float4 c4[4];
#pragma unroll
        for (int jj = 0; jj < 4; ++jj) {
            const bool up = (lane & 16) != 0;
            float4 keep = up ? c8[jj + 4] : c8[jj];
            float4 give = up ? c8[jj] : c8[jj + 4];
            c4[jj] = add4(keep, shfl_xor4(give, 16));
        }
        float4 c2[2];
#pragma unroll
        for (int jj = 0; jj < 2; ++jj) {
            const bool up = (lane & 8) != 0;
            float4 keep = up ? c4[jj + 2] : c4[jj];
            float4 give = up ? c4[jj] : c4[jj + 2];
            c2[jj] = add4(keep, shfl_xor4(give, 8));
        }
        float4 c1;
        {
            const bool up = (lane & 4) != 0;
            float4 keep = up ? c2[1] : c2[0];
            float4 give = up ? c2[0] : c2[1];
            c1 = add4(keep, shfl_xor4(give, 4));
        }
        float p0, p1;
        {
            const bool up = (lane & 2) != 0;
            float kx = up ? c1.z : c1.x, gx = up ? c1.x : c1.z;
            float ky = up ? c1.w : c1.y, gy = up ? c1.y : c1.w;
            p0 = kx + __shfl_xor(gx, 2, 64);
            p1 = ky + __shfl_xor(gy, 2, 64);
        }
        float s_part;
        {
            const bool up = (lane & 1) != 0;
            float k1 = up ? p1 : p0, g1 = up ? p0 : p1;
            s_part = k1 + __shfl_xor(g1, 1, 64);
        }
        partial[(w << 6) + lane] = s_part;
        __syncthreads();

        if (tid < 64) {
            const float inv = 1.0f / (wsum[0] + wsum[1] + wsum[2]
                                    + wsum[3] + wsum[4]);
            float sraw = (partial[tid] + partial[64 + tid] + partial[128 + tid]
                        + partial[192 + tid] + partial[256 + tid]) * inv;
            float s  = tanhf(sraw);
            float ss = s * s;
#pragma unroll
            for (int off = 1; off < 64; off <<= 1)
                ss += __shfl_xor(ss, off, 64);
            float n = sqrtf(ss) + EPSF;
            m_lds[tid] = s * n / (1.0f + n * n);
        }
        __syncthreads();
    }

    if (tid < 64)
        out[(((size_t)b * Mdim + i) << 6) + tid] = m_lds[tid];
}

// ---------------------------------------------------------------------------
extern "C" void kernel_launch(void* const* d_in, const int* in_sizes, int n_in,
                              void* d_out, int out_size, void* d_ws, size_t ws_size,
                              hipStream_t stream) {
    const float* M_emb  = (const float*)d_in[0];
    const float* Ht     = (const float*)d_in[1];
    const float* m_init = (const float*)d_in[2];
    const float* W      = (const float*)d_in[3];
    float* out = (float*)d_out;
    float* u   = (float*)d_ws;

    const size_t per_i = (size_t)Bdim * MTdim * Ddim * sizeof(float);
    int icap = (int)(ws_size / per_i);
    if (icap > Mdim) icap = Mdim;
    if (icap < 1) icap = 1;

    for (int i0 = 0; i0 < Mdim; i0 += icap) {
        int ic = Mdim - i0 < icap ? Mdim - i0 : icap;
        dim3 g1(MTdim / 2, ic);
        u_kernel<<<g1, dim3(256), 0, stream>>>(M_emb, Ht, W, u, i0, icap);
        dim3 g2(ic, Bdim);
        iter_kernel<<<g2, dim3(320), 0, stream>>>(u, m_init, out, i0, icap);
    }
}

// Round 5
// 97.089 us; speedup vs baseline: 1.1112x; 1.1112x over previous
//
#include <hip/hip_runtime.h>

#define Bdim 8
#define Mdim 64
#define Tdim 256
#define MTdim 320
#define Ddim 64
#define EPSF 1e-4f

__device__ __forceinline__ void load_lds16(const void* g, void* l) {
    __builtin_amdgcn_global_load_lds(
        (const __attribute__((address_space(1))) void*)g,
        (__attribute__((address_space(3))) void*)l, 16, 0, 0);
}

// ---------------------------------------------------------------------------
// Phase 1 (= R3, the 96.3µs version): u[b,i,t,d] = sum_k W[i,t,d,k]*cat[b,t,k]
// One block (4 waves) per (i,t); 16 KB W tile staged via global_load_lds,
// XOR-swizzled content (chunk k4 of row d at byte d*256 + ((k4^(d&7))*16)),
// source pre-swizzled, linear LDS dest. Wave w computes batches 2w, 2w+1.
// ---------------------------------------------------------------------------
__global__ __launch_bounds__(256) void u_kernel(
    const float* __restrict__ M_emb,
    const float* __restrict__ Ht,
    const float* __restrict__ W,
    float* __restrict__ u,
    int i0, int icap)
{
    const int t   = blockIdx.x;                  // 0..319
    const int ii  = blockIdx.y;
    const int i   = i0 + ii;
    const int tid = (int)threadIdx.x;
    const int l   = tid & 63;
    const int w   = __builtin_amdgcn_readfirstlane(tid >> 6);  // wave 0..3

    __shared__ __align__(16) float wtile[64 * 64];   // 16 KB swizzled
    char* ldsb = (char*)wtile;

    const char* wt = (const char*)(W + (((size_t)i * MTdim + t) << 12));

#pragma unroll
    for (int s = 0; s < 4; ++s) {
        const int r   = w * 16 + s * 4 + (l >> 4);       // row d
        const int src = (r * 256 + ((l & 15) * 16)) ^ ((r & 7) * 16);
        load_lds16(wt + src, ldsb + (w * 4096 + s * 1024));
    }

    const int b0 = 2 * w, b1 = 2 * w + 1;
    const float* c0;
    const float* c1;
    if (t < Mdim) {
        c0 = M_emb + (((size_t)b0 * Mdim + t) << 6);
        c1 = M_emb + (((size_t)b1 * Mdim + t) << 6);
    } else {
        c0 = Ht + (((size_t)b0 * Tdim + (t - Mdim)) << 6);
        c1 = Ht + (((size_t)b1 * Tdim + (t - Mdim)) << 6);
    }

    __syncthreads();   // drains vmcnt(0) -> tile resident

    const int rbase = l * 256 + (l & 7) * 16;
    float a0 = 0.0f, a1 = 0.0f;
#pragma unroll
    for (int k4 = 0; k4 < 16; ++k4) {
        const float4 w4 = *reinterpret_cast<const float4*>(ldsb + (rbase ^ (k4 * 16)));
        const float4 p  = *reinterpret_cast<const float4*>(c0 + (k4 << 2));
        const float4 q  = *reinterpret_cast<const float4*>(c1 + (k4 << 2));
        a0 = fmaf(w4.x, p.x, a0); a0 = fmaf(w4.y, p.y, a0);
        a0 = fmaf(w4.z, p.z, a0); a0 = fmaf(w4.w, p.w, a0);
        a1 = fmaf(w4.x, q.x, a1); a1 = fmaf(w4.y, q.y, a1);
        a1 = fmaf(w4.z, q.z, a1); a1 = fmaf(w4.w, q.w, a1);
    }

    u[((((size_t)b0 * icap + ii) * MTdim + t) << 6) + l] = a0;
    u[((((size_t)b1 * icap + ii) * MTdim + t) << 6) + l] = a1;
}

// ---------------------------------------------------------------------------
// Phase 2 v3: one block (320 thr) per (b,i). The 80-KB u slice is staged
// into LDS in two 40-KB chunks via coalesced global_load_lds (1 KB/instr,
// XOR-swizzled via pre-swizzled source), then each thread ds_read_b128s
// its row into registers. Iterations identical to R2.
// ---------------------------------------------------------------------------
__device__ __forceinline__ float4 shfl_xor4(float4 v, int m) {
    float4 r;
    r.x = __shfl_xor(v.x, m, 64);
    r.y = __shfl_xor(v.y, m, 64);
    r.z = __shfl_xor(v.z, m, 64);
    r.w = __shfl_xor(v.w, m, 64);
    return r;
}
__device__ __forceinline__ float4 add4(float4 a, float4 b) {
    float4 r; r.x = a.x + b.x; r.y = a.y + b.y; r.z = a.z + b.z; r.w = a.w + b.w;
    return r;
}

__global__ __launch_bounds__(320) void iter_kernel(
    const float* __restrict__ u,
    const float* __restrict__ m_init,
    float* __restrict__ out,
    int i0, int icap)
{
    const int ii   = blockIdx.x;
    const int i    = i0 + ii;
    const int b    = blockIdx.y;
    const int tid  = (int)threadIdx.x;   // 0..319 == row t
    const int lane = tid & 63;
    const int w    = tid >> 6;           // 0..4
    const int wu   = __builtin_amdgcn_readfirstlane(w);

    const char* ubc = (const char*)(u + ((((size_t)b * icap + ii) * MTdim) << 6));

    __shared__ __align__(16) float u_lds[160 * 64];   // 40 KB chunk buffer
    __shared__ __align__(16) float m_lds[Ddim];
    __shared__ float wmax[5], wsum[5];
    __shared__ float partial[5 * 64];
    char* ldsb = (char*)u_lds;

    float4 u4[16];

    // ---- stage chunk 0 (rows 0..159): 8 x 1KB per wave, coalesced ----
#pragma unroll
    for (int s = 0; s < 8; ++s) {
        const int r   = (wu * 8 + s) * 4 + (lane >> 4);   // row in chunk
        const int src = r * 256 + ((((lane & 15)) ^ (r & 7)) * 16);
        load_lds16(ubc + src, ldsb + ((wu * 8 + s) * 1024));
    }

    if (tid < Ddim)
        m_lds[tid] = m_init[(((size_t)b * Mdim + i) << 6) + tid];

    __syncthreads();   // chunk 0 resident

    if (tid < 160) {
        const int rbase = tid * 256 + (tid & 7) * 16;
#pragma unroll
        for (int k4 = 0; k4 < 16; ++k4)
            u4[k4] = *reinterpret_cast<const float4*>(ldsb + (rbase ^ (k4 * 16)));
    }
    __syncthreads();   // reads done before overwrite

    // ---- stage chunk 1 (rows 160..319) ----
#pragma unroll
    for (int s = 0; s < 8; ++s) {
        const int r   = (wu * 8 + s) * 4 + (lane >> 4);
        const int src = 160 * 256 + r * 256 + ((((lane & 15)) ^ (r & 7)) * 16);
        load_lds16(ubc + src, ldsb + ((wu * 8 + s) * 1024));
    }
    __syncthreads();   // chunk 1 resident

    if (tid >= 160) {
        const int rl    = tid - 160;
        const int rbase = rl * 256 + (rl & 7) * 16;
#pragma unroll
        for (int k4 = 0; k4 < 16; ++k4)
            u4[k4] = *reinterpret_cast<const float4*>(ldsb + (rbase ^ (k4 * 16)));
    }
    __syncthreads();

    for (int iter = 0; iter < 3; ++iter) {
        // ---- pass A: logit bt = dot(m, u_row) — lane-local ---------------
        float bt = 0.0f;
#pragma unroll
        for (int k4 = 0; k4 < 16; ++k4) {
            float4 mv = *reinterpret_cast<const float4*>(&m_lds[k4 << 2]);
            bt = fmaf(u4[k4].x, mv.x, bt);
            bt = fmaf(u4[k4].y, mv.y, bt);
            bt = fmaf(u4[k4].z, mv.z, bt);
            bt = fmaf(u4[k4].w, mv.w, bt);
        }

        // ---- block max over 320 logits ----------------------------------
        float mx = bt;
#pragma unroll
        for (int off = 1; off < 64; off <<= 1)
            mx = fmaxf(mx, __shfl_xor(mx, off, 64));
        if (lane == 0) wmax[w] = mx;
        __syncthreads();
        const float bmax = fmaxf(fmaxf(fmaxf(wmax[0], wmax[1]),
                                       fmaxf(wmax[2], wmax[3])), wmax[4]);

        const float e = expf(bt - bmax);

        float sm = e;
#pragma unroll
        for (int off = 1; off < 64; off <<= 1)
            sm += __shfl_xor(sm, off, 64);
        if (lane == 0) wsum[w] = sm;

        // ---- pass B: distributed reduce of e*u_row across the wave ------
        float4 c8[8];
#pragma unroll
        for (int jj = 0; jj < 8; ++jj) {
            const bool up = (lane & 32) != 0;
            float4 keep = up ? u4[jj + 8] : u4[jj];
            float4 give = up ? u4[jj] : u4[jj + 8];
            float4 g; g.x = give.x * e; g.y = give.y * e;
                      g.z = give.z * e; g.w = give.w * e;
            float4 r = shfl_xor4(g, 32);
            float4 o;
            o.x = fmaf(keep.x, e, r.x); o.y = fmaf(keep.y, e, r.y);
            o.z = fmaf(keep.z, e, r.z); o.w = fmaf(keep.w, e, r.w);
            c8[jj] = o;
        }
        float4 c4[4];
#pragma unroll
        for (int jj = 0; jj < 4; ++jj) {
            const bool up = (lane & 16) != 0;
            float4 keep = up ? c8[jj + 4] : c8[jj];
            float4 give = up ? c8[jj] : c8[jj + 4];
            c4[jj] = add4(keep, shfl_xor4(give, 16));
        }
        float4 c2[2];
#pragma unroll
        for (int jj = 0; jj < 2; ++jj) {
            const bool up = (lane & 8) != 0;
            float4 keep = up ? c4[jj + 2] : c4[jj];
            float4 give = up ? c4[jj] : c4[jj + 2];
            c2[jj] = add4(keep, shfl_xor4(give, 8));
        }
        float4 c1;
        {
            const bool up = (lane & 4) != 0;
            float4 keep = up ? c2[1] : c2[0];
            float4 give = up ? c2[0] : c2[1];
            c1 = add4(keep, shfl_xor4(give, 4));
        }
        float p0, p1;
        {
            const bool up = (lane & 2) != 0;
            float kx = up ? c1.z : c1.x, gx = up ? c1.x : c1.z;
            float ky = up ? c1.w : c1.y, gy = up ? c1.y : c1.w;
            p0 = kx + __shfl_xor(gx, 2, 64);
            p1 = ky + __shfl_xor(gy, 2, 64);
        }
        float s_part;
        {
            const bool up = (lane & 1) != 0;
            float k1 = up ? p1 : p0, g1 = up ? p0 : p1;
            s_part = k1 + __shfl_xor(g1, 1, 64);
        }
        partial[(w << 6) + lane] = s_part;
        __syncthreads();

        // ---- combine + tanh + squash (wave 0) ---------------------------
        if (tid < 64) {
            const float inv = 1.0f / (wsum[0] + wsum[1] + wsum[2]
                                    + wsum[3] + wsum[4]);
            float sraw = (partial[tid] + partial[64 + tid] + partial[128 + tid]
                        + partial[192 + tid] + partial[256 + tid]) * inv;
            float s  = tanhf(sraw);
            float ss = s * s;
#pragma unroll
            for (int off = 1; off < 64; off <<= 1)
                ss += __shfl_xor(ss, off, 64);
            float n = sqrtf(ss) + EPSF;
            m_lds[tid] = s * n / (1.0f + n * n);
        }
        __syncthreads();
    }

    if (tid < 64)
        out[(((size_t)b * Mdim + i) << 6) + tid] = m_lds[tid];
}

// ---------------------------------------------------------------------------
extern "C" void kernel_launch(void* const* d_in, const int* in_sizes, int n_in,
                              void* d_out, int out_size, void* d_ws, size_t ws_size,
                              hipStream_t stream) {
    const float* M_emb  = (const float*)d_in[0];
    const float* Ht     = (const float*)d_in[1];
    const float* m_init = (const float*)d_in[2];
    const float* W      = (const float*)d_in[3];
    float* out = (float*)d_out;
    float* u   = (float*)d_ws;

    const size_t per_i = (size_t)Bdim * MTdim * Ddim * sizeof(float);
    int icap = (int)(ws_size / per_i);
    if (icap > Mdim) icap = Mdim;
    if (icap < 1) icap = 1;

    for (int i0 = 0; i0 < Mdim; i0 += icap) {
        int ic = Mdim - i0 < icap ? Mdim - i0 : icap;
        dim3 g1(MTdim, ic);
        u_kernel<<<g1, dim3(256), 0, stream>>>(M_emb, Ht, W, u, i0, icap);
        dim3 g2(ic, Bdim);
        iter_kernel<<<g2, dim3(320), 0, stream>>>(u, m_init, out, i0, icap);
    }
}

// Round 6
// 95.082 us; speedup vs baseline: 1.1347x; 1.0211x over previous
//
#include <hip/hip_runtime.h>

#define Bdim 8
#define Mdim 64
#define Tdim 256
#define MTdim 320
#define Ddim 64
#define EPSF 1e-4f

__device__ __forceinline__ void load_lds16(const void* g, void* l) {
    __builtin_amdgcn_global_load_lds(
        (const __attribute__((address_space(1))) void*)g,
        (__attribute__((address_space(3))) void*)l, 16, 0, 0);
}

// ---------------------------------------------------------------------------
// Phase 1 v4: u[b,i,t,d] = sum_k W[i,t,d,k] * cat[b,t,k]
// One block (4 waves) per (i,t), ZERO barriers: wave w owns d-quarter
// [16w,16w+16); lane l -> d = 16w + (l>>2), batches {l&3, (l&3)+4}.
// Each wave stages its own 4-KB W quarter + a duplicate 2-KB swizzled cat
// copy (identical bytes from all waves -> benign), waits vmcnt(0)
// privately, computes. LDS swizzles: W row r chunk k4 at slot k4^(r&7);
// cat row b chunk k4 at slot k4^b. Sources pre-swizzled (rule #21).
// ---------------------------------------------------------------------------
__global__ __launch_bounds__(256) void u_kernel(
    const float* __restrict__ M_emb,
    const float* __restrict__ Ht,
    const float* __restrict__ W,
    float* __restrict__ u,
    int i0, int icap)
{
    const int t   = blockIdx.x;                  // 0..319
    const int ii  = blockIdx.y;
    const int i   = i0 + ii;
    const int tid = (int)threadIdx.x;
    const int l   = tid & 63;
    const int w   = __builtin_amdgcn_readfirstlane(tid >> 6);  // wave 0..3

    __shared__ __align__(16) float wtile[64 * 64];   // 16 KB, swizzled
    __shared__ __align__(16) float catb[8 * 64];     // 2 KB, swizzled
    char* wl = (char*)wtile;
    char* cl = (char*)catb;

    // ---- cat staging: every wave stages all 8 rows (dup writes benign) ----
#pragma unroll
    for (int c = 0; c < 2; ++c) {
        const int b = 4 * c + (l >> 4);
        const float* crow = (t < Mdim)
            ? (M_emb + (((size_t)b * Mdim + t) << 6))
            : (Ht   + (((size_t)b * Tdim + (t - Mdim)) << 6));
        load_lds16((const char*)crow + (((l & 15) ^ b) * 16), cl + c * 1024);
    }

    // ---- W quarter staging: wave w stages rows [16w, 16w+16) ----
    const char* wt = (const char*)(W + (((size_t)i * MTdim + t) << 12));
#pragma unroll
    for (int s = 0; s < 4; ++s) {
        const int r   = w * 16 + s * 4 + (l >> 4);
        const int src = r * 256 + (((l & 15) ^ (r & 7)) * 16);
        load_lds16(wt + src, wl + (w * 4096 + s * 1024));
    }

    // wave-private drain of this wave's own 6 loads; no cross-wave barrier
    asm volatile("s_waitcnt vmcnt(0)" ::: "memory");
    __builtin_amdgcn_sched_barrier(0);

    const int d   = w * 16 + (l >> 2);
    const int bp  = l & 3;
    const int wb  = d * 256;
    const int cb0 = bp * 256;
    const int cb1 = (bp + 4) * 256;

    float a0 = 0.0f, a1 = 0.0f;
#pragma unroll
    for (int k4 = 0; k4 < 16; ++k4) {
        const float4 w4 = *reinterpret_cast<const float4*>(wl + wb  + ((k4 ^ (d & 7)) * 16));
        const float4 p  = *reinterpret_cast<const float4*>(cl + cb0 + ((k4 ^ bp) * 16));
        const float4 q  = *reinterpret_cast<const float4*>(cl + cb1 + ((k4 ^ (bp + 4)) * 16));
        a0 = fmaf(w4.x, p.x, a0); a0 = fmaf(w4.y, p.y, a0);
        a0 = fmaf(w4.z, p.z, a0); a0 = fmaf(w4.w, p.w, a0);
        a1 = fmaf(w4.x, q.x, a1); a1 = fmaf(w4.y, q.y, a1);
        a1 = fmaf(w4.z, q.z, a1); a1 = fmaf(w4.w, q.w, a1);
    }

    // u layout: [b][ii][t][d], i-stride = icap
    u[((((size_t)bp      * icap + ii) * MTdim + t) << 6) + d] = a0;
    u[((((size_t)(bp + 4)* icap + ii) * MTdim + t) << 6) + d] = a1;
}

// ---------------------------------------------------------------------------
// Phase 2 (= R3/R2, measured-equal to LDS-staged variant): one block of
// 320 threads per (b,i); thread t holds u[t,0:63] in registers.
// ---------------------------------------------------------------------------
__device__ __forceinline__ float4 shfl_xor4(float4 v, int m) {
    float4 r;
    r.x = __shfl_xor(v.x, m, 64);
    r.y = __shfl_xor(v.y, m, 64);
    r.z = __shfl_xor(v.z, m, 64);
    r.w = __shfl_xor(v.w, m, 64);
    return r;
}
__device__ __forceinline__ float4 add4(float4 a, float4 b) {
    float4 r; r.x = a.x + b.x; r.y = a.y + b.y; r.z = a.z + b.z; r.w = a.w + b.w;
    return r;
}

__global__ __launch_bounds__(320) void iter_kernel(
    const float* __restrict__ u,
    const float* __restrict__ m_init,
    float* __restrict__ out,
    int i0, int icap)
{
    const int ii   = blockIdx.x;
    const int i    = i0 + ii;
    const int b    = blockIdx.y;
    const int tid  = (int)threadIdx.x;   // 0..319 == row t
    const int lane = tid & 63;
    const int w    = tid >> 6;           // 0..4

    const float* ub = u + ((((size_t)b * icap + ii) * MTdim) << 6);

    __shared__ __align__(16) float m_lds[Ddim];
    __shared__ float wmax[5], wsum[5];
    __shared__ float partial[5 * 64];

    float4 u4[16];
    {
        const float* row = ub + ((size_t)tid << 6);
#pragma unroll
        for (int k4 = 0; k4 < 16; ++k4)
            u4[k4] = *reinterpret_cast<const float4*>(row + (k4 << 2));
    }

    if (tid < Ddim)
        m_lds[tid] = m_init[(((size_t)b * Mdim + i) << 6) + tid];
    __syncthreads();

    for (int iter = 0; iter < 3; ++iter) {
        float bt = 0.0f;
#pragma unroll
        for (int k4 = 0; k4 < 16; ++k4) {
            float4 mv = *reinterpret_cast<const float4*>(&m_lds[k4 << 2]);
            bt = fmaf(u4[k4].x, mv.x, bt);
            bt = fmaf(u4[k4].y, mv.y, bt);
            bt = fmaf(u4[k4].z, mv.z, bt);
            bt = fmaf(u4[k4].w, mv.w, bt);
        }

        float mx = bt;
#pragma unroll
        for (int off = 1; off < 64; off <<= 1)
            mx = fmaxf(mx, __shfl_xor(mx, off, 64));
        if (lane == 0) wmax[w] = mx;
        __syncthreads();
        const float bmax = fmaxf(fmaxf(fmaxf(wmax[0], wmax[1]),
                                       fmaxf(wmax[2], wmax[3])), wmax[4]);

        const float e = expf(bt - bmax);

        float sm = e;
#pragma unroll
        for (int off = 1; off < 64; off <<= 1)
            sm += __shfl_xor(sm, off, 64);
        if (lane == 0) wsum[w] = sm;

        float4 c8[8];
#pragma unroll
        for (int jj = 0; jj < 8; ++jj) {
            const bool up = (lane & 32) != 0;
            float4 keep = up ? u4[jj + 8] : u4[jj];
            float4 give = up ? u4[jj] : u4[jj + 8];
            float4 g; g.x = give.x * e; g.y = give.y * e;
                      g.z = give.z * e; g.w = give.w * e;
            float4 r = shfl_xor4(g, 32);
            float4 o;
            o.x = fmaf(keep.x, e, r.x); o.y = fmaf(keep.y, e, r.y);
            o.z = fmaf(keep.z, e, r.z); o.w = fmaf(keep.w, e, r.w);
            c8[jj] = o;
        }
        float4 c4[4];
#pragma unroll
        for (int jj = 0; jj < 4; ++jj) {
            const bool up = (lane & 16) != 0;
            float4 keep = up ? c8[jj + 4] : c8[jj];
            float4 give = up ? c8[jj] : c8[jj + 4];
            c4[jj] = add4(keep, shfl_xor4(give, 16));
        }
        float4 c2[2];
#pragma unroll
        for (int jj = 0; jj < 2; ++jj) {
            const bool up = (lane & 8) != 0;
            float4 keep = up ? c4[jj + 2] : c4[jj];
            float4 give = up ? c4[jj] : c4[jj + 2];
            c2[jj] = add4(keep, shfl_xor4(give, 8));
        }
        float4 c1;
        {
            const bool up = (lane & 4) != 0;
            float4 keep = up ? c2[1] : c2[0];
            float4 give = up ? c2[0] : c2[1];
            c1 = add4(keep, shfl_xor4(give, 4));
        }
        float p0, p1;
        {
            const bool up = (lane & 2) != 0;
            float kx = up ? c1.z : c1.x, gx = up ? c1.x : c1.z;
            float ky = up ? c1.w : c1.y, gy = up ? c1.y : c1.w;
            p0 = kx + __shfl_xor(gx, 2, 64);
            p1 = ky + __shfl_xor(gy, 2, 64);
        }
        float s_part;
        {
            const bool up = (lane & 1) != 0;
            float k1 = up ? p1 : p0, g1 = up ? p0 : p1;
            s_part = k1 + __shfl_xor(g1, 1, 64);
        }
        partial[(w << 6) + lane] = s_part;
        __syncthreads();

        if (tid < 64) {
            const float inv = 1.0f / (wsum[0] + wsum[1] + wsum[2]
                                    + wsum[3] + wsum[4]);
            float sraw = (partial[tid] + partial[64 + tid] + partial[128 + tid]
                        + partial[192 + tid] + partial[256 + tid]) * inv;
            float s  = tanhf(sraw);
            float ss = s * s;
#pragma unroll
            for (int off = 1; off < 64; off <<= 1)
                ss += __shfl_xor(ss, off, 64);
            float n = sqrtf(ss) + EPSF;
            m_lds[tid] = s * n / (1.0f + n * n);
        }
        __syncthreads();
    }

    if (tid < 64)
        out[(((size_t)b * Mdim + i) << 6) + tid] = m_lds[tid];
}

// ---------------------------------------------------------------------------
extern "C" void kernel_launch(void* const* d_in, const int* in_sizes, int n_in,
                              void* d_out, int out_size, void* d_ws, size_t ws_size,
                              hipStream_t stream) {
    const float* M_emb  = (const float*)d_in[0];
    const float* Ht     = (const float*)d_in[1];
    const float* m_init = (const float*)d_in[2];
    const float* W      = (const float*)d_in[3];
    float* out = (float*)d_out;
    float* u   = (float*)d_ws;

    const size_t per_i = (size_t)Bdim * MTdim * Ddim * sizeof(float);
    int icap = (int)(ws_size / per_i);
    if (icap > Mdim) icap = Mdim;
    if (icap < 1) icap = 1;

    for (int i0 = 0; i0 < Mdim; i0 += icap) {
        int ic = Mdim - i0 < icap ? Mdim - i0 : icap;
        dim3 g1(MTdim, ic);
        u_kernel<<<g1, dim3(256), 0, stream>>>(M_emb, Ht, W, u, i0, icap);
        dim3 g2(ic, Bdim);
        iter_kernel<<<g2, dim3(320), 0, stream>>>(u, m_init, out, i0, icap);
    }
}